// Round 10
// baseline (3259.653 us; speedup 1.0000x reference)
//
#include <hip/hip_runtime.h>
#include <math.h>

#define S_LEN 256
#define BATCH 64
#define NIN   1024
#define NH    2048
#define SCAN_BLOCKS  128   // 16 cols each
#define SCAN_THREADS 512   // 8 waves, K-split 8x256
#define H_SLOTS 8          // h rotation depth; inv only at wrap

typedef short s16x8 __attribute__((ext_vector_type(8)));
typedef float f32x4 __attribute__((ext_vector_type(4)));
typedef float f32x2 __attribute__((ext_vector_type(2)));
typedef unsigned short u16x4 __attribute__((ext_vector_type(4)));

__device__ inline unsigned short f2bf(float f){
  unsigned int u = __float_as_uint(f);
  u += 0x7fffu + ((u >> 16) & 1u);      // round-to-nearest-even
  return (unsigned short)(u >> 16);
}

__global__ void k_cast_bf16(const float* __restrict__ in,
                            unsigned short* __restrict__ out, int n4){
  int i = blockIdx.x * blockDim.x + threadIdx.x;
  if (i >= n4) return;
  float4 v = ((const float4*)in)[i];
  u16x4 o;
  o.x = f2bf(v.x); o.y = f2bf(v.y); o.z = f2bf(v.z); o.w = f2bf(v.w);
  ((u16x4*)out)[i] = o;
}

// out[n][k] = bf16(in[k][n]);  K,N multiples of 32
__global__ void k_transpose_bf16(const float* __restrict__ in,
                                 unsigned short* __restrict__ out, int K, int N){
  __shared__ unsigned short tile[32][33];
  int n0 = blockIdx.x * 32, k0 = blockIdx.y * 32;
  int tx = threadIdx.x, ty = threadIdx.y;   // 32 x 8
  #pragma unroll
  for (int i = 0; i < 4; ++i)
    tile[ty + i*8][tx] = f2bf(in[(size_t)(k0 + ty + i*8) * N + n0 + tx]);
  __syncthreads();
  #pragma unroll
  for (int i = 0; i < 4; ++i)
    out[(size_t)(n0 + ty + i*8) * K + k0 + tx] = tile[tx][ty + i*8];
}

// base = x @ Wx + bx + bh  (fp32 into d_out)
__global__ __launch_bounds__(256) void k_xproj(
    const unsigned short* __restrict__ xbf,   // [16384][1024] bf16
    const unsigned short* __restrict__ wxt,   // [2048][1024]  bf16 (Wx^T)
    const float* __restrict__ bx,
    const float* __restrict__ bh,
    float* __restrict__ out)                  // [16384][2048] fp32
{
  int wave = threadIdx.x >> 6, lane = threadIdx.x & 63;
  int q = lane >> 4, r = lane & 15;
  int m0 = blockIdx.y * 64 + wave * 16;
  int n0 = blockIdx.x * 64;

  const unsigned short* arow = xbf + (size_t)(m0 + r) * NIN + q * 8;
  const unsigned short* brow = wxt + (size_t)(n0 + r) * NIN + q * 8;

  f32x4 acc[4] = {};
  #pragma unroll 2
  for (int kk = 0; kk < NIN; kk += 32){
    s16x8 a = *(const s16x8*)(arow + kk);
    #pragma unroll
    for (int j = 0; j < 4; ++j){
      s16x8 b = *(const s16x8*)(brow + (size_t)j * 16 * NIN + kk);
      acc[j] = __builtin_amdgcn_mfma_f32_16x16x32_bf16(a, b, acc[j], 0, 0, 0);
    }
  }
  #pragma unroll
  for (int j = 0; j < 4; ++j){
    int col = n0 + j * 16 + r;
    float bias = bx[col] + bh[col];
    #pragma unroll
    for (int i = 0; i < 4; ++i){
      int row = m0 + q * 4 + i;
      out[(size_t)row * NH + col] = acc[j][i] + bias;
    }
  }
}

// Persistent weight-stationary scan, v10 = v9 skeleton at 128 blocks x 16 cols.
// v9 confirmed the MALL-latency x miss-concurrency model (step 13.2 -> 9.6us
// from the prefetch alone). The h broadcast's MALL bytes are fixed at
// 8 XCD x 256 KB/step (co-XCD misses merge in L2), so doubling consumer
// blocks doubles outstanding misses per XCD-L2 with no added traffic, and
// wakes 64 more CUs (Occupancy 6.2% -> ~12%).
// Sync skeleton is v9 verbatim, scaled: block-wide wave0 poll of ALL 128
// flags (2 per lane), wrap-only (t%8==0) agent-acquire inv, syncthreads (C);
// plain-WB out stores; sc0/sc1 hn stores drained by syncthreads (B) before
// the relaxed flag store; 8-slot h rotation, layout [64][2048] unchanged.
// Per-block halving: breg 8 frags (one 16-col n-tile), 32 MFMA/wave,
// red[8][64][20] = 40 KB LDS (2 blocks/CU now fit).
__global__ __launch_bounds__(SCAN_THREADS, 2) void k_scan_persist(
    unsigned short* __restrict__ hbuf,      // H_SLOTS x [64][2048] bf16 (slot0 = h0)
    const unsigned short* __restrict__ wht, // [2048][2048] bf16 (Wh^T)
    float* __restrict__ out,                // [256][64][2048] fp32 (base in, tanh out)
    unsigned int* __restrict__ flags)       // 128 flags, stride 4 uints (16B), zeroed
{
  __shared__ float red[8][BATCH][20];

  const int tid = threadIdx.x;
  const int wave = tid >> 6, lane = tid & 63;
  const int q = lane >> 4, r = lane & 15;
  const int n0 = blockIdx.x * 16;
  const int kbase = wave * 256;

  // ---- preload Wh^T slice into registers (once): 1 n-tile x 8 k-tiles ----
  s16x8 breg[8];
  #pragma unroll
  for (int kk = 0; kk < 8; ++kk)
    breg[kk] = *(const s16x8*)(wht + (size_t)(n0 + r) * NH + kbase + kk*32 + q*8);

  const int crow = tid >> 3;        // 0..63  (epilogue mapping)
  const int ccol = (tid & 7) * 2;   // 0,2,..,14
  const size_t g = (size_t)crow * NH + n0 + ccol;

  // base for t=0 (plain load; only k_xproj has written these addresses)
  f32x2 base = *(const f32x2*)(out + g);

  for (int t = 0; t < S_LEN; ++t){
    const unsigned short* hc = hbuf + (size_t)(t & (H_SLOTS-1)) * BATCH * NH;
    unsigned short* hn       = hbuf + (size_t)((t + 1) & (H_SLOTS-1)) * BATCH * NH;
    float* outT = out + (size_t)t * BATCH * NH;

    // ---- wait: all 128 blocks finished step t-1 (v9 skeleton, scaled) ----
    if (t > 0){
      if (wave == 0){
        const unsigned int target = (unsigned int)t;
        const unsigned int* f0 = flags + ((unsigned)lane << 2);
        const unsigned int* f1 = flags + ((unsigned)(lane + 64) << 2);
        for (;;){
          unsigned int a = __hip_atomic_load(f0, __ATOMIC_RELAXED, __HIP_MEMORY_SCOPE_AGENT);
          unsigned int b = __hip_atomic_load(f1, __ATOMIC_RELAXED, __HIP_MEMORY_SCOPE_AGENT);
          if (__all((int)(a >= target && b >= target))) break;
        }
        // inv L1+L2 only at rotation wrap: clears lines cached 8 steps ago
        if ((t & (H_SLOTS-1)) == 0)
          __builtin_amdgcn_fence(__ATOMIC_ACQUIRE, "agent");
      }
      __syncthreads();              // (C) release waves 1..7; orders their h loads
    }

    // ---- full prefetch: all 32 h fragment loads in flight, then MFMA ----
    s16x8 a[8][4];
    #pragma unroll
    for (int kk = 0; kk < 8; ++kk)
      #pragma unroll
      for (int m = 0; m < 4; ++m)
        a[kk][m] = *(const s16x8*)(hc + (size_t)(m*16 + r) * NH + kbase + kk*32 + q*8);

    f32x4 acc[4] = {};
    #pragma unroll
    for (int kk = 0; kk < 8; ++kk)
      #pragma unroll
      for (int m = 0; m < 4; ++m)
        acc[m] = __builtin_amdgcn_mfma_f32_16x16x32_bf16(a[kk][m], breg[kk], acc[m], 0, 0, 0);

    // ---- single-pass K-reduce staging: all 8 waves write partials ----
    #pragma unroll
    for (int m = 0; m < 4; ++m)
      #pragma unroll
      for (int i = 0; i < 4; ++i)
        red[wave][m*16 + q*4 + i][r] = acc[m][i];
    __syncthreads();                // (A)

    // ---- epilogue: all 512 threads, 2 elems each ----
    {
      float s0 = 0.f, s1 = 0.f;
      #pragma unroll
      for (int w = 0; w < 8; ++w){
        s0 += red[w][crow][ccol];
        s1 += red[w][crow][ccol + 1];
      }
      float tv0 = tanhf(base[0] + s0);
      float tv1 = tanhf(base[1] + s1);

      // out: PLAIN cached write-back store (nobody reads out during the scan;
      // kernel-end release publishes dirty lines)
      f32x2 ov; ov[0] = tv0; ov[1] = tv1;
      *(f32x2*)(outT + g) = ov;

      // hn: device-scope write-through (consumers on other XCDs read it)
      union { unsigned short h[2]; unsigned int u; } ph;
      ph.h[0] = f2bf(tv0); ph.h[1] = f2bf(tv1);
      __hip_atomic_store((unsigned int*)(hn + g), ph.u,
                         __ATOMIC_RELAXED, __HIP_MEMORY_SCOPE_AGENT);
    }

    __syncthreads();                // (B) vmcnt(0) drain => sc1 hn stores at MALL
    if (tid == 0)
      __hip_atomic_store(flags + ((unsigned)blockIdx.x << 2), (unsigned int)(t + 1),
                         __ATOMIC_RELAXED, __HIP_MEMORY_SCOPE_AGENT);

    // prefetch next step's base (plain; written only by k_xproj and later by
    // this block itself -> L1-coherent for its only reader)
    if (t + 1 < S_LEN)
      base = *(const f32x2*)(out + (size_t)(t + 1) * BATCH * NH + g);
  }
}

extern "C" void kernel_launch(void* const* d_in, const int* in_sizes, int n_in,
                              void* d_out, int out_size, void* d_ws, size_t ws_size,
                              hipStream_t stream){
  const float* x  = (const float*)d_in[0];
  const float* h0 = (const float*)d_in[1];
  const float* Wx = (const float*)d_in[2];
  const float* bx = (const float*)d_in[3];
  const float* Wh = (const float*)d_in[4];
  const float* bh = (const float*)d_in[5];
  float* out = (float*)d_out;

  char* ws = (char*)d_ws;
  unsigned short* xbf  = (unsigned short*)(ws);                               // 33,554,432 B
  unsigned short* wxt  = (unsigned short*)(ws + 33554432);                    //  4,194,304 B
  unsigned short* wht  = (unsigned short*)(ws + 33554432 + 4194304);          //  8,388,608 B
  // flags (128 x 16B) at ws[0..2KB); hbuf (8 slots x 256KB = 2MB) at ws+4096.
  // Both alias xbf, which is dead after k_xproj; h0 is cast into slot 0 only
  // after k_xproj completes (stream order). hbuf does NOT overlap wxt/wht.
  unsigned int* flags = (unsigned int*)ws;
  unsigned short* hbuf = (unsigned short*)(ws + 4096);

  // 1) cast x to bf16
  k_cast_bf16<<<dim3(16384), 256, 0, stream>>>(x, xbf, 4194304);
  // 2) weight transposes to [n][k] bf16
  k_transpose_bf16<<<dim3(NH/32, NIN/32), dim3(32, 8), 0, stream>>>(Wx, wxt, NIN, NH);
  k_transpose_bf16<<<dim3(NH/32, NH/32),  dim3(32, 8), 0, stream>>>(Wh, wht, NH, NH);
  // 3) base = x@Wx + bx + bh -> d_out
  k_xproj<<<dim3(NH/64, (S_LEN*BATCH)/64), 256, 0, stream>>>(xbf, wxt, bx, bh, out);
  // 4) xbf now dead: cast h0 into hbuf slot 0, zero flags, run scan
  k_cast_bf16<<<dim3(128), 256, 0, stream>>>(h0, hbuf, 32768);
  hipMemsetAsync(flags, 0, 2048, stream);
  {
    void* args[] = { (void*)&hbuf, (void*)&wht, (void*)&out, (void*)&flags };
    hipLaunchCooperativeKernel((const void*)k_scan_persist,
                               dim3(SCAN_BLOCKS), dim3(SCAN_THREADS), args, 0, stream);
  }
  // 5) hn = outputs[255]
  hipMemcpyAsync(out + (size_t)S_LEN * BATCH * NH,
                 out + (size_t)(S_LEN - 1) * BATCH * NH,
                 sizeof(float) * (size_t)BATCH * NH,
                 hipMemcpyDeviceToDevice, stream);
}

// Round 11
// 3222.908 us; speedup vs baseline: 1.0114x; 1.0114x over previous
//
#include <hip/hip_runtime.h>
#include <math.h>

#define S_LEN 256
#define BATCH 64
#define NIN   1024
#define NH    2048
#define SCAN_BLOCKS  64    // 32 cols each
#define SCAN_THREADS 512   // 8 waves, K-split 8x256
#define H_SLOTS 8          // h rotation depth; inv only at wrap

typedef short s16x8 __attribute__((ext_vector_type(8)));
typedef float f32x4 __attribute__((ext_vector_type(4)));
typedef unsigned short u16x4 __attribute__((ext_vector_type(4)));

__device__ inline unsigned short f2bf(float f){
  unsigned int u = __float_as_uint(f);
  u += 0x7fffu + ((u >> 16) & 1u);      // round-to-nearest-even
  return (unsigned short)(u >> 16);
}

__global__ void k_cast_bf16(const float* __restrict__ in,
                            unsigned short* __restrict__ out, int n4){
  int i = blockIdx.x * blockDim.x + threadIdx.x;
  if (i >= n4) return;
  float4 v = ((const float4*)in)[i];
  u16x4 o;
  o.x = f2bf(v.x); o.y = f2bf(v.y); o.z = f2bf(v.z); o.w = f2bf(v.w);
  ((u16x4*)out)[i] = o;
}

// out[n][k] = bf16(in[k][n]);  K,N multiples of 32
__global__ void k_transpose_bf16(const float* __restrict__ in,
                                 unsigned short* __restrict__ out, int K, int N){
  __shared__ unsigned short tile[32][33];
  int n0 = blockIdx.x * 32, k0 = blockIdx.y * 32;
  int tx = threadIdx.x, ty = threadIdx.y;   // 32 x 8
  #pragma unroll
  for (int i = 0; i < 4; ++i)
    tile[ty + i*8][tx] = f2bf(in[(size_t)(k0 + ty + i*8) * N + n0 + tx]);
  __syncthreads();
  #pragma unroll
  for (int i = 0; i < 4; ++i)
    out[(size_t)(n0 + ty + i*8) * K + k0 + tx] = tile[tx][ty + i*8];
}

// base = x @ Wx + bx + bh  (fp32 into d_out)
__global__ __launch_bounds__(256) void k_xproj(
    const unsigned short* __restrict__ xbf,   // [16384][1024] bf16
    const unsigned short* __restrict__ wxt,   // [2048][1024]  bf16 (Wx^T)
    const float* __restrict__ bx,
    const float* __restrict__ bh,
    float* __restrict__ out)                  // [16384][2048] fp32
{
  int wave = threadIdx.x >> 6, lane = threadIdx.x & 63;
  int q = lane >> 4, r = lane & 15;
  int m0 = blockIdx.y * 64 + wave * 16;
  int n0 = blockIdx.x * 64;

  const unsigned short* arow = xbf + (size_t)(m0 + r) * NIN + q * 8;
  const unsigned short* brow = wxt + (size_t)(n0 + r) * NIN + q * 8;

  f32x4 acc[4] = {};
  #pragma unroll 2
  for (int kk = 0; kk < NIN; kk += 32){
    s16x8 a = *(const s16x8*)(arow + kk);
    #pragma unroll
    for (int j = 0; j < 4; ++j){
      s16x8 b = *(const s16x8*)(brow + (size_t)j * 16 * NIN + kk);
      acc[j] = __builtin_amdgcn_mfma_f32_16x16x32_bf16(a, b, acc[j], 0, 0, 0);
    }
  }
  #pragma unroll
  for (int j = 0; j < 4; ++j){
    int col = n0 + j * 16 + r;
    float bias = bx[col] + bh[col];
    #pragma unroll
    for (int i = 0; i < 4; ++i){
      int row = m0 + q * 4 + i;
      out[(size_t)row * NH + col] = acc[j][i] + bias;
    }
  }
}

// Persistent weight-stationary scan, v11 = v9 + NONTEMPORAL out/base streams.
// v10 diagnosis: FETCH_SIZE shows ~1 MB/step of h refills served from HBM —
// the 128MB out-write + 128MB base-read streams cycle the 256MB MALL and
// evict the 2MB h working set between production and consumption, making the
// h broadcast an HBM-latency round trip (~9.6us/step).
// Fix (one theme): out tanh-stores use __builtin_nontemporal_store and base
// loads use __builtin_nontemporal_load — no L2/MALL allocation, so the
// write-once/read-once streams stop thrashing the MALL and h stays
// MALL-resident. Correctness argument identical to v6/v9 plain stores:
// nobody reads out during the scan; base addresses are written only by
// k_xproj (pre-scan) and overwritten only by this block one step later.
// Sync skeleton, prefetch, slot rotation: v9 verbatim (passed, 2457us).
__global__ __launch_bounds__(SCAN_THREADS, 2) void k_scan_persist(
    unsigned short* __restrict__ hbuf,      // H_SLOTS x [64][2048] bf16 (slot0 = h0)
    const unsigned short* __restrict__ wht, // [2048][2048] bf16 (Wh^T)
    float* __restrict__ out,                // [256][64][2048] fp32 (base in, tanh out)
    unsigned int* __restrict__ flags)       // 64 flags, stride 4 uints (16B), zeroed
{
  __shared__ float red[8][BATCH][36];

  const int tid = threadIdx.x;
  const int wave = tid >> 6, lane = tid & 63;
  const int q = lane >> 4, r = lane & 15;
  const int n0 = blockIdx.x * 32;
  const int kbase = wave * 256;

  // ---- preload Wh^T slice into registers (once): 2 n-tiles x 8 k-tiles ----
  s16x8 breg[2][8];
  #pragma unroll
  for (int kk = 0; kk < 8; ++kk)
    #pragma unroll
    for (int j = 0; j < 2; ++j)
      breg[j][kk] = *(const s16x8*)(wht + (size_t)(n0 + j*16 + r) * NH + kbase + kk*32 + q*8);

  const int crow = tid >> 3;        // 0..63  (epilogue mapping)
  const int ccol = (tid & 7) * 4;   // 0..28
  const size_t g = (size_t)crow * NH + n0 + ccol;

  // base for t=0: nontemporal (read-once stream; no MALL pollution)
  f32x4 base = __builtin_nontemporal_load((const f32x4*)(out + g));

  for (int t = 0; t < S_LEN; ++t){
    const unsigned short* hc = hbuf + (size_t)(t & (H_SLOTS-1)) * BATCH * NH;
    unsigned short* hn       = hbuf + (size_t)((t + 1) & (H_SLOTS-1)) * BATCH * NH;
    float* outT = out + (size_t)t * BATCH * NH;

    // ---- wait: all blocks finished step t-1 (v9 skeleton, proven) ----
    if (t > 0){
      if (wave == 0){
        const unsigned int target = (unsigned int)t;
        const unsigned int* fp = flags + (lane << 2);   // 16B-strided flag per lane
        for (;;){
          unsigned int v = __hip_atomic_load(fp, __ATOMIC_RELAXED, __HIP_MEMORY_SCOPE_AGENT);
          if (__all((int)(v >= target))) break;
        }
        // inv L1+L2 only at rotation wrap: clears lines cached 8 steps ago
        if ((t & (H_SLOTS-1)) == 0)
          __builtin_amdgcn_fence(__ATOMIC_ACQUIRE, "agent");
      }
      __syncthreads();              // (C) release waves 1..7; orders their h loads
    }

    // ---- full prefetch: all 32 h fragment loads in flight, then MFMA ----
    s16x8 a[8][4];
    #pragma unroll
    for (int kk = 0; kk < 8; ++kk)
      #pragma unroll
      for (int m = 0; m < 4; ++m)
        a[kk][m] = *(const s16x8*)(hc + (size_t)(m*16 + r) * NH + kbase + kk*32 + q*8);

    f32x4 acc[4][2] = {};
    #pragma unroll
    for (int kk = 0; kk < 8; ++kk)
      #pragma unroll
      for (int m = 0; m < 4; ++m)
        #pragma unroll
        for (int j = 0; j < 2; ++j)
          acc[m][j] = __builtin_amdgcn_mfma_f32_16x16x32_bf16(a[kk][m], breg[j][kk], acc[m][j], 0, 0, 0);

    // ---- single-pass K-reduce staging: all 8 waves write partials ----
    #pragma unroll
    for (int m = 0; m < 4; ++m)
      #pragma unroll
      for (int j = 0; j < 2; ++j)
        #pragma unroll
        for (int i = 0; i < 4; ++i)
          red[wave][m*16 + q*4 + i][j*16 + r] = acc[m][j][i];
    __syncthreads();                // (A)

    // ---- epilogue: all 512 threads, 4 elems each ----
    {
      f32x4 s = *(const f32x4*)&red[0][crow][ccol];
      #pragma unroll
      for (int w = 1; w < 8; ++w)
        s += *(const f32x4*)&red[w][crow][ccol];
      f32x4 tv;
      #pragma unroll
      for (int i = 0; i < 4; ++i) tv[i] = tanhf(base[i] + s[i]);

      // out: NONTEMPORAL store (write-once; bypass L2/MALL allocation so the
      // out stream does not evict the h working set from the MALL)
      __builtin_nontemporal_store(tv, (f32x4*)(outT + g));

      // hn: device-scope write-through (consumers on other XCDs read it)
      union { unsigned short h[4]; unsigned long long u; } ph;
      #pragma unroll
      for (int i = 0; i < 4; ++i) ph.h[i] = f2bf(tv[i]);
      __hip_atomic_store((unsigned long long*)(hn + g), ph.u,
                         __ATOMIC_RELAXED, __HIP_MEMORY_SCOPE_AGENT);
    }

    __syncthreads();                // (B) vmcnt(0) drain => sc1 hn stores at MALL
    if (tid == 0)
      __hip_atomic_store(flags + ((unsigned)blockIdx.x << 2), (unsigned int)(t + 1),
                         __ATOMIC_RELAXED, __HIP_MEMORY_SCOPE_AGENT);

    // prefetch next step's base: nontemporal (read-once stream)
    if (t + 1 < S_LEN)
      base = __builtin_nontemporal_load((const f32x4*)(out + (size_t)(t + 1) * BATCH * NH + g));
  }
}

extern "C" void kernel_launch(void* const* d_in, const int* in_sizes, int n_in,
                              void* d_out, int out_size, void* d_ws, size_t ws_size,
                              hipStream_t stream){
  const float* x  = (const float*)d_in[0];
  const float* h0 = (const float*)d_in[1];
  const float* Wx = (const float*)d_in[2];
  const float* bx = (const float*)d_in[3];
  const float* Wh = (const float*)d_in[4];
  const float* bh = (const float*)d_in[5];
  float* out = (float*)d_out;

  char* ws = (char*)d_ws;
  unsigned short* xbf  = (unsigned short*)(ws);                               // 33,554,432 B
  unsigned short* wxt  = (unsigned short*)(ws + 33554432);                    //  4,194,304 B
  unsigned short* wht  = (unsigned short*)(ws + 33554432 + 4194304);          //  8,388,608 B
  // flags (64 x 16B) at ws[0..1KB); hbuf (8 slots x 256KB = 2MB) at ws+4096.
  // Both alias xbf, which is dead after k_xproj; h0 is cast into slot 0 only
  // after k_xproj completes (stream order). hbuf does NOT overlap wxt/wht.
  unsigned int* flags = (unsigned int*)ws;
  unsigned short* hbuf = (unsigned short*)(ws + 4096);

  // 1) cast x to bf16
  k_cast_bf16<<<dim3(16384), 256, 0, stream>>>(x, xbf, 4194304);
  // 2) weight transposes to [n][k] bf16
  k_transpose_bf16<<<dim3(NH/32, NIN/32), dim3(32, 8), 0, stream>>>(Wx, wxt, NIN, NH);
  k_transpose_bf16<<<dim3(NH/32, NH/32),  dim3(32, 8), 0, stream>>>(Wh, wht, NH, NH);
  // 3) base = x@Wx + bx + bh -> d_out
  k_xproj<<<dim3(NH/64, (S_LEN*BATCH)/64), 256, 0, stream>>>(xbf, wxt, bx, bh, out);
  // 4) xbf now dead: cast h0 into hbuf slot 0, zero flags, run scan
  k_cast_bf16<<<dim3(128), 256, 0, stream>>>(h0, hbuf, 32768);
  hipMemsetAsync(flags, 0, 1024, stream);
  {
    void* args[] = { (void*)&hbuf, (void*)&wht, (void*)&out, (void*)&flags };
    hipLaunchCooperativeKernel((const void*)k_scan_persist,
                               dim3(SCAN_BLOCKS), dim3(SCAN_THREADS), args, 0, stream);
  }
  // 5) hn = outputs[255]
  hipMemcpyAsync(out + (size_t)S_LEN * BATCH * NH,
                 out + (size_t)(S_LEN - 1) * BATCH * NH,
                 sizeof(float) * (size_t)BATCH * NH,
                 hipMemcpyDeviceToDevice, stream);
}